// Round 8
// baseline (393.829 us; speedup 1.0000x reference)
//
#include <hip/hip_runtime.h>

#define NN   50000
#define NE   800000
#define IND  128
#define HIDD 96
#define OUTD 128
#define CATD (4 * HIDD)   // 384
#define CAP  64

typedef __attribute__((ext_vector_type(8))) short short8v;
typedef __attribute__((ext_vector_type(4))) float f32x4;

__device__ __forceinline__ ushort f2bf(float f) {
    unsigned u = __float_as_uint(f);
    u = (u + 0x7FFFu + ((u >> 16) & 1u)) >> 16;
    return (ushort)u;
}
__device__ __forceinline__ float bf2f(ushort h) {
    return __uint_as_float(((unsigned)h) << 16);
}

// ---------------------------------------------------------------------------
// Weight regions (in whi/wlo):
//  [0, NW_IN)                row-major W_in   [96][128]
//  [NW_IN, NW_IN+NW_L)       row-major W_layers
//  [.., NW_ROW)              row-major W_out  [128][384]
//  [NW_ROW, NW_ROW+NW_L)     frag-ordered W_layers: [l][c<6][ks<3][lane<64][8]
//  [NW_ROW+NW_L, NW_ALL)     frag-ordered W_out:    [c<8][ks<12][lane<64][8]
// frag entry (c,ks,lane,t) = W[c*16 + (lane&15)][ks*32 + 8*(lane>>4) + t]
// ---------------------------------------------------------------------------
#define NW_IN  (HIDD * IND)          // 12288
#define NW_L   (3 * HIDD * HIDD)     // 27648
#define NW_OUT (OUTD * CATD)         // 49152
#define NW_ROW (NW_IN + NW_L + NW_OUT)
#define NW_ALL (NW_ROW + NW_L + NW_OUT)

__global__ __launch_bounds__(256)
void wsplit_k(const float* __restrict__ Wi, const float* __restrict__ Wl,
              const float* __restrict__ Wo,
              ushort* __restrict__ whi, ushort* __restrict__ wlo)
{
    int i = blockIdx.x * 256 + threadIdx.x;
    if (i >= NW_ALL) return;
    float v;
    if (i < NW_ROW) {
        if (i < NW_IN)              v = Wi[i];
        else if (i < NW_IN + NW_L)  v = Wl[i - NW_IN];
        else                        v = Wo[i - NW_IN - NW_L];
    } else if (i < NW_ROW + NW_L) {
        int fi = i - NW_ROW;
        int l  = fi / 9216;
        int r  = fi - l * 9216;
        int c  = r / 1536;
        int ks = (r % 1536) / 512;
        int ln = (r % 512) / 8;
        int t  = r & 7;
        int j  = c * 16 + (ln & 15);
        int k  = ks * 32 + 8 * (ln >> 4) + t;
        v = Wl[(l * HIDD + j) * HIDD + k];
    } else {
        int fi = i - NW_ROW - NW_L;
        int c  = fi / 6144;
        int r  = fi - c * 6144;
        int ks = r / 512;
        int ln = (r % 512) / 8;
        int t  = r & 7;
        int j  = c * 16 + (ln & 15);
        int k  = ks * 32 + 8 * (ln >> 4) + t;
        v = Wo[j * CATD + k];
    }
    ushort h = f2bf(v);
    whi[i] = h;
    wlo[i] = f2bf(v - bf2f(h));
}

// ---------------------------------------------------------------------------
// MFMA GEMM (row-major W staged in LDS), C stride parametrized.
// ---------------------------------------------------------------------------
template<int K, int NCOLS, int ROWS, bool ACCUM>
__global__ __launch_bounds__(256)
void mgemm_k(const float* __restrict__ A,
             const ushort* __restrict__ Whi, const ushort* __restrict__ Wlo,
             int wstride, const float* __restrict__ bias,
             float* __restrict__ C, int cstride, int nrows)
{
    constexpr int ST  = K + 8;
    constexpr int KS  = K / 32;
    constexpr int TRP = (ROWS / 16) / 2;
    constexpr int TCP = (NCOLS / 16) / 2;
    constexpr int CPR = K / 8;

    __shared__ __align__(16) ushort sWh[NCOLS * ST];
    __shared__ __align__(16) ushort sWl[NCOLS * ST];

    const int tid  = threadIdx.x;
    const int w    = tid >> 6;
    const int l    = tid & 63;
    const int lr   = l & 15;
    const int lg   = l >> 4;
    const int row0 = blockIdx.x * ROWS;

    for (int idx = tid; idx < NCOLS * CPR; idx += 256) {
        int j = idx / CPR, c = idx - j * CPR;
        *(uint4*)&sWh[j * ST + c * 8] = *(const uint4*)&Whi[(long)j * wstride + c * 8];
        *(uint4*)&sWl[j * ST + c * 8] = *(const uint4*)&Wlo[(long)j * wstride + c * 8];
    }

    short8v Ah[TRP][KS], Al[TRP][KS];
#pragma unroll
    for (int i = 0; i < TRP; i++) {
        const int row = row0 + ((w >> 1) + 2 * i) * 16 + lr;
#pragma unroll
        for (int ks = 0; ks < KS; ks++) {
            float4 r0 = make_float4(0.f, 0.f, 0.f, 0.f);
            float4 r1 = make_float4(0.f, 0.f, 0.f, 0.f);
            if (row < nrows) {
                const float* p = &A[(long)row * K + ks * 32 + 8 * lg];
                r0 = *(const float4*)p;
                r1 = *(const float4*)(p + 4);
            }
            const float f[8] = {r0.x, r0.y, r0.z, r0.w, r1.x, r1.y, r1.z, r1.w};
            short8v hi, lo;
#pragma unroll
            for (int t = 0; t < 8; t++) {
                ushort h = f2bf(f[t]);
                hi[t] = (short)h;
                lo[t] = (short)f2bf(f[t] - bf2f(h));
            }
            Ah[i][ks] = hi;
            Al[i][ks] = lo;
        }
    }
    __syncthreads();

#pragma unroll
    for (int j = 0; j < TCP; j++) {
        const int colb = ((w & 1) + 2 * j) * 16;
        short8v Bh[KS], Bl[KS];
#pragma unroll
        for (int ks = 0; ks < KS; ks++) {
            Bh[ks] = *(const short8v*)&sWh[(colb + lr) * ST + ks * 32 + 8 * lg];
            Bl[ks] = *(const short8v*)&sWl[(colb + lr) * ST + ks * 32 + 8 * lg];
        }
        const float bv = bias ? bias[colb + lr] : 0.f;
#pragma unroll
        for (int i = 0; i < TRP; i++) {
            f32x4 acc = {bv, bv, bv, bv};
#pragma unroll
            for (int ks = 0; ks < KS; ks++) {
                acc = __builtin_amdgcn_mfma_f32_16x16x32_bf16(Ah[i][ks], Bh[ks], acc, 0, 0, 0);
                acc = __builtin_amdgcn_mfma_f32_16x16x32_bf16(Ah[i][ks], Bl[ks], acc, 0, 0, 0);
                acc = __builtin_amdgcn_mfma_f32_16x16x32_bf16(Al[i][ks], Bh[ks], acc, 0, 0, 0);
            }
#pragma unroll
            for (int p = 0; p < 4; p++) {
                const int row = row0 + ((w >> 1) + 2 * i) * 16 + 4 * lg + p;
                if (row < nrows) {
                    float* cp = &C[(long)row * cstride + colb + lr];
                    if (ACCUM) *cp += acc[p];
                    else       *cp  = acc[p];
                }
            }
        }
    }
}

// ---------------------------------------------------------------------------
// One-pass capped-bucket CSR, 4 edges/thread for ILP.
// ---------------------------------------------------------------------------
__global__ __launch_bounds__(256)
void fillb_k(const int* __restrict__ ei, int* __restrict__ cursor,
             int* __restrict__ bucket)
{
    unsigned int e0 = (blockIdx.x * 256u + threadIdx.x) * 4u;
    if (e0 + 4 <= (unsigned int)NE) {
        const int4 s4 = *(const int4*)&ei[e0];
        const int4 d4 = *(const int4*)&ei[NE + e0];
        int p0 = atomicAdd(&cursor[d4.x], 1);
        int p1 = atomicAdd(&cursor[d4.y], 1);
        int p2 = atomicAdd(&cursor[d4.z], 1);
        int p3 = atomicAdd(&cursor[d4.w], 1);
        if (p0 < CAP) bucket[(long)d4.x * CAP + p0] = s4.x;
        if (p1 < CAP) bucket[(long)d4.y * CAP + p1] = s4.y;
        if (p2 < CAP) bucket[(long)d4.z * CAP + p2] = s4.z;
        if (p3 < CAP) bucket[(long)d4.w * CAP + p3] = s4.w;
    } else {
        for (unsigned int e = e0; e < (unsigned int)NE; e++) {
            int s = ei[e];
            int d = ei[NE + e];
            int pos = atomicAdd(&cursor[d], 1);
            if (pos < CAP) bucket[(long)d * CAP + pos] = s;
        }
    }
}

// Pad each bucket row to a multiple of 4 with sentinel NN (zero row).
__global__ __launch_bounds__(256)
void padb_k(const int* __restrict__ cursor, int* __restrict__ bucket)
{
    int n = blockIdx.x * 256 + threadIdx.x;
    if (n >= NN) return;
    int cnt = cursor[n];
    if (cnt > CAP) cnt = CAP;
    int cnt4 = (cnt + 3) & ~3;
    int* bp = &bucket[(long)n * CAP];
    for (int p = cnt; p < cnt4; p++) bp[p] = NN;
}

// ---------------------------------------------------------------------------
// Fused layer v3: 128 thr = 16 nodes; gather with int4 index loads + 4-row
// ILP; MFMA with frag-W from global (L2-resident). LDS 6.4 KB.
// Sentinel index NN reads the zeroed row NN of the h slab.
// ---------------------------------------------------------------------------
#define FROWS 16
#define FAST  100

__global__ __launch_bounds__(128)
void flayer_k(const float* __restrict__ h_in, int istride,
              const int* __restrict__ cursor, const int* __restrict__ bucket,
              const ushort* __restrict__ fWhi, const ushort* __restrict__ fWlo,
              const float* __restrict__ bias,
              float* __restrict__ h_out, int ostride)
{
    __shared__ __align__(16) float sA[FROWS * FAST];

    const int tid = threadIdx.x;
    const int n0  = blockIdx.x * FROWS;

    // gather self + neighbors (8 threads/node x 12 floats)
    {
        const int i  = tid >> 3;
        const int st = tid & 7;
        const int n  = n0 + i;
        const float* hbase = h_in + st * 12;
        float4 s0, s1, s2;
        {
            const float* hp = &hbase[(long)n * istride];
            s0 = ((const float4*)hp)[0];
            s1 = *(const float4*)(hp + 4);
            s2 = *(const float4*)(hp + 8);
        }
        int cnt = cursor[n];
        if (cnt > CAP) cnt = CAP;
        const int cnt4 = (cnt + 3) & ~3;
        const int* bp = &bucket[(long)n * CAP];
        for (int e = 0; e < cnt4; e += 4) {
            const int4 id = *(const int4*)&bp[e];
            const float* q0 = &hbase[(long)id.x * istride];
            const float* q1 = &hbase[(long)id.y * istride];
            const float* q2 = &hbase[(long)id.z * istride];
            const float* q3 = &hbase[(long)id.w * istride];
            const float4 a0 = ((const float4*)q0)[0];
            const float4 b0 = *(const float4*)(q0 + 4);
            const float4 c0 = *(const float4*)(q0 + 8);
            const float4 a1 = ((const float4*)q1)[0];
            const float4 b1 = *(const float4*)(q1 + 4);
            const float4 c1 = *(const float4*)(q1 + 8);
            const float4 a2 = ((const float4*)q2)[0];
            const float4 b2 = *(const float4*)(q2 + 4);
            const float4 c2 = *(const float4*)(q2 + 8);
            const float4 a3 = ((const float4*)q3)[0];
            const float4 b3 = *(const float4*)(q3 + 4);
            const float4 c3 = *(const float4*)(q3 + 8);
            s0.x += (a0.x + a1.x) + (a2.x + a3.x);
            s0.y += (a0.y + a1.y) + (a2.y + a3.y);
            s0.z += (a0.z + a1.z) + (a2.z + a3.z);
            s0.w += (a0.w + a1.w) + (a2.w + a3.w);
            s1.x += (b0.x + b1.x) + (b2.x + b3.x);
            s1.y += (b0.y + b1.y) + (b2.y + b3.y);
            s1.z += (b0.z + b1.z) + (b2.z + b3.z);
            s1.w += (b0.w + b1.w) + (b2.w + b3.w);
            s2.x += (c0.x + c1.x) + (c2.x + c3.x);
            s2.y += (c0.y + c1.y) + (c2.y + c3.y);
            s2.z += (c0.z + c1.z) + (c2.z + c3.z);
            s2.w += (c0.w + c1.w) + (c2.w + c3.w);
        }
        float* ap = &sA[i * FAST + st * 12];
        ((float4*)ap)[0] = s0;
        ((float4*)ap)[1] = s1;
        ((float4*)ap)[2] = s2;
    }
    __syncthreads();

    const int w  = tid >> 6;      // 0..1
    const int l  = tid & 63;
    const int lr = l & 15;
    const int lg = l >> 4;

    short8v Ah[3], Al[3];
#pragma unroll
    for (int ks = 0; ks < 3; ks++) {
        const float* ap = &sA[lr * FAST + ks * 32 + 8 * lg];
        const float4 r0 = ((const float4*)ap)[0];
        const float4 r1 = ((const float4*)ap)[1];
        const float f[8] = {r0.x, r0.y, r0.z, r0.w, r1.x, r1.y, r1.z, r1.w};
        short8v hi, lo;
#pragma unroll
        for (int t = 0; t < 8; t++) {
            ushort h = f2bf(f[t]);
            hi[t] = (short)h;
            lo[t] = (short)f2bf(f[t] - bf2f(h));
        }
        Ah[ks] = hi;
        Al[ks] = lo;
    }

#pragma unroll
    for (int j = 0; j < 3; j++) {
        const int c    = w + 2 * j;          // 6 col tiles across 2 waves
        const int colb = c * 16;
        short8v Bh[3], Bl[3];
#pragma unroll
        for (int ks = 0; ks < 3; ks++) {
            Bh[ks] = *(const short8v*)&fWhi[((c * 3 + ks) * 64 + l) * 8];
            Bl[ks] = *(const short8v*)&fWlo[((c * 3 + ks) * 64 + l) * 8];
        }
        const float bv = bias[colb + lr];
        f32x4 acc = {bv, bv, bv, bv};
#pragma unroll
        for (int ks = 0; ks < 3; ks++) {
            acc = __builtin_amdgcn_mfma_f32_16x16x32_bf16(Ah[ks], Bh[ks], acc, 0, 0, 0);
            acc = __builtin_amdgcn_mfma_f32_16x16x32_bf16(Ah[ks], Bl[ks], acc, 0, 0, 0);
            acc = __builtin_amdgcn_mfma_f32_16x16x32_bf16(Al[ks], Bh[ks], acc, 0, 0, 0);
        }
#pragma unroll
        for (int p = 0; p < 4; p++) {
            const int row = n0 + 4 * lg + p;
            if (row < NN)
                h_out[(long)row * ostride + colb + lr] = acc[p];
        }
    }
}

// ---------------------------------------------------------------------------
// Final GEMM: out[NN][128] = cat[NN][384] @ W_out^T + b_out
// ---------------------------------------------------------------------------
__global__ __launch_bounds__(256)
void fgemm_k(const float* __restrict__ cat, const ushort* __restrict__ fOhi,
             const ushort* __restrict__ fOlo, const float* __restrict__ bias,
             float* __restrict__ out)
{
    const int tid  = threadIdx.x;
    const int w    = tid >> 6;
    const int l    = tid & 63;
    const int lr   = l & 15;
    const int lg   = l >> 4;
    const int row0 = blockIdx.x * 64;

    f32x4 acc[2][4];
#pragma unroll
    for (int j = 0; j < 4; j++) {
        const float bv = bias[((w & 1) + 2 * j) * 16 + lr];
#pragma unroll
        for (int i = 0; i < 2; i++) acc[i][j] = (f32x4){bv, bv, bv, bv};
    }

#pragma unroll 4
    for (int ks = 0; ks < 12; ks++) {
        short8v Ah[2], Al[2];
#pragma unroll
        for (int i = 0; i < 2; i++) {
            const int row = row0 + ((w >> 1) + 2 * i) * 16 + lr;
            float4 r0 = make_float4(0.f, 0.f, 0.f, 0.f);
            float4 r1 = make_float4(0.f, 0.f, 0.f, 0.f);
            if (row < NN) {
                const float* p = &cat[(long)row * CATD + ks * 32 + 8 * lg];
                r0 = *(const float4*)p;
                r1 = *(const float4*)(p + 4);
            }
            const float f[8] = {r0.x, r0.y, r0.z, r0.w, r1.x, r1.y, r1.z, r1.w};
            short8v hi, lo;
#pragma unroll
            for (int t = 0; t < 8; t++) {
                ushort h = f2bf(f[t]);
                hi[t] = (short)h;
                lo[t] = (short)f2bf(f[t] - bf2f(h));
            }
            Ah[i] = hi;
            Al[i] = lo;
        }
#pragma unroll
        for (int j = 0; j < 4; j++) {
            const int c = (w & 1) + 2 * j;
            const short8v Bh = *(const short8v*)&fOhi[((c * 12 + ks) * 64 + l) * 8];
            const short8v Bl = *(const short8v*)&fOlo[((c * 12 + ks) * 64 + l) * 8];
#pragma unroll
            for (int i = 0; i < 2; i++) {
                acc[i][j] = __builtin_amdgcn_mfma_f32_16x16x32_bf16(Ah[i], Bh, acc[i][j], 0, 0, 0);
                acc[i][j] = __builtin_amdgcn_mfma_f32_16x16x32_bf16(Ah[i], Bl, acc[i][j], 0, 0, 0);
                acc[i][j] = __builtin_amdgcn_mfma_f32_16x16x32_bf16(Al[i], Bh, acc[i][j], 0, 0, 0);
            }
        }
    }

#pragma unroll
    for (int i = 0; i < 2; i++) {
#pragma unroll
        for (int p = 0; p < 4; p++) {
            const int row = row0 + ((w >> 1) + 2 * i) * 16 + 4 * lg + p;
            if (row < NN) {
#pragma unroll
                for (int j = 0; j < 4; j++)
                    out[(long)row * OUTD + ((w & 1) + 2 * j) * 16 + lr] = acc[i][j][p];
            }
        }
    }
}

// ---------------------------------------------------------------------------
extern "C" void kernel_launch(void* const* d_in, const int* in_sizes, int n_in,
                              void* d_out, int out_size, void* d_ws, size_t ws_size,
                              hipStream_t stream)
{
    const float* x  = (const float*)d_in[0];
    const int*   ei = (const int*)  d_in[1];
    const float* Wi = (const float*)d_in[2];
    const float* bi = (const float*)d_in[3];
    const float* Wl = (const float*)d_in[4];
    const float* bl = (const float*)d_in[5];
    const float* Wo = (const float*)d_in[6];
    const float* bo = (const float*)d_in[7];
    float* out = (float*)d_out;

    char* p = (char*)d_ws;
    int* cursor = (int*)p;                 p += ((size_t)NN * 4 + 255) & ~255ull;
    int* bucket = (int*)p;                 p += ((size_t)NN * CAP * 4 + 255) & ~255ull;
    ushort* whi = (ushort*)p;              p += ((size_t)NW_ALL * 2 + 255) & ~255ull;
    ushort* wlo = (ushort*)p;              p += ((size_t)NW_ALL * 2 + 255) & ~255ull;
    float* big  = (float*)p;
    const size_t used = (size_t)(p - (char*)d_ws);
    const bool catpath = (ws_size >= used + (size_t)(NN + 1) * CATD * 4);

    const ushort* whi_in = whi;
    const ushort* wlo_in = wlo;
    const ushort* whi_o  = whi + NW_IN + NW_L;
    const ushort* wlo_o  = wlo + NW_IN + NW_L;
    const ushort* fLhi   = whi + NW_ROW;
    const ushort* fLlo   = wlo + NW_ROW;
    const ushort* fOhi   = whi + NW_ROW + NW_L;
    const ushort* fOlo   = wlo + NW_ROW + NW_L;

    hipLaunchKernelGGL(wsplit_k, dim3((NW_ALL + 255) / 256), dim3(256), 0, stream,
                       Wi, Wl, Wo, whi, wlo);
    hipMemsetAsync(cursor, 0, (size_t)NN * sizeof(int), stream);
    hipLaunchKernelGGL(fillb_k, dim3((NE / 4 + 255) / 256), dim3(256), 0, stream,
                       ei, cursor, bucket);
    hipLaunchKernelGGL(padb_k, dim3((NN + 255) / 256), dim3(256), 0, stream,
                       cursor, bucket);

    if (catpath) {
        float* cat = big;                          // [(NN+1)][384], row NN = zeros
        hipMemsetAsync(cat + (size_t)NN * CATD, 0, CATD * sizeof(float), stream);
        hipLaunchKernelGGL((mgemm_k<IND, HIDD, 32, false>),
                           dim3((NN + 31) / 32), dim3(256), 0, stream,
                           x, whi_in, wlo_in, IND, bi, cat, CATD, NN);
        for (int l = 0; l < 3; l++) {
            hipLaunchKernelGGL(flayer_k, dim3((NN + FROWS - 1) / FROWS), dim3(128), 0, stream,
                               cat + (size_t)l * HIDD, CATD, cursor, bucket,
                               fLhi + (size_t)l * 9216, fLlo + (size_t)l * 9216,
                               bl + (size_t)l * HIDD,
                               cat + (size_t)(l + 1) * HIDD, CATD);
        }
        hipLaunchKernelGGL(fgemm_k, dim3((NN + 63) / 64), dim3(256), 0, stream,
                           cat, fOhi, fOlo, bo, out);
    } else {
        float* hA = big;                           // [(NN+1)][96]
        float* hB = hA + (size_t)(NN + 1) * HIDD;  // [(NN+1)][96]
        hipMemsetAsync(hA + (size_t)NN * HIDD, 0, HIDD * sizeof(float), stream);
        hipMemsetAsync(hB + (size_t)NN * HIDD, 0, HIDD * sizeof(float), stream);
        hipLaunchKernelGGL((mgemm_k<IND, HIDD, 32, false>),
                           dim3((NN + 31) / 32), dim3(256), 0, stream,
                           x, whi_in, wlo_in, IND, bi, hA, HIDD, NN);
        hipLaunchKernelGGL((mgemm_k<HIDD, OUTD, 64, false>),
                           dim3((NN + 63) / 64), dim3(256), 0, stream,
                           hA, whi_o, wlo_o, CATD, bo, out, OUTD, NN);
        const float* hsrc = hA;
        float*       hdst = hB;
        for (int l = 0; l < 3; l++) {
            hipLaunchKernelGGL(flayer_k, dim3((NN + FROWS - 1) / FROWS), dim3(128), 0, stream,
                               hsrc, HIDD, cursor, bucket,
                               fLhi + (size_t)l * 9216, fLlo + (size_t)l * 9216,
                               bl + (size_t)l * HIDD, hdst, HIDD);
            hipLaunchKernelGGL((mgemm_k<HIDD, OUTD, 64, true>),
                               dim3((NN + 63) / 64), dim3(256), 0, stream,
                               hdst, whi_o + (size_t)(l + 1) * HIDD,
                               wlo_o + (size_t)(l + 1) * HIDD, CATD,
                               (const float*)nullptr, out, OUTD, NN);
            const float* t = hsrc; hsrc = hdst; hdst = (float*)t;
        }
    }
}

// Round 9
// 329.765 us; speedup vs baseline: 1.1943x; 1.1943x over previous
//
#include <hip/hip_runtime.h>

#define NN   50000
#define NE   800000
#define IND  128
#define HIDD 96
#define OUTD 128
#define CATD (4 * HIDD)   // 384
#define CAP  64

typedef __attribute__((ext_vector_type(8))) short short8v;
typedef __attribute__((ext_vector_type(4))) float f32x4;

__device__ __forceinline__ ushort f2bf(float f) {
    unsigned u = __float_as_uint(f);
    u = (u + 0x7FFFu + ((u >> 16) & 1u)) >> 16;
    return (ushort)u;
}
__device__ __forceinline__ float bf2f(ushort h) {
    return __uint_as_float(((unsigned)h) << 16);
}
__device__ __forceinline__ float blo(unsigned u) { return __uint_as_float(u << 16); }
__device__ __forceinline__ float bhi(unsigned u) { return __uint_as_float(u & 0xffff0000u); }

// ---------------------------------------------------------------------------
// Weight regions (in whi/wlo):
//  [0, NW_IN)                row-major W_in   [96][128]
//  [NW_IN, NW_IN+NW_L)       row-major W_layers
//  [.., NW_ROW)              row-major W_out  [128][384]
//  [NW_ROW, NW_ROW+NW_L)     frag-ordered W_layers: [l][c<6][ks<3][lane<64][8]
//  [NW_ROW+NW_L, NW_ALL)     frag-ordered W_out:    [c<8][ks<12][lane<64][8]
// ---------------------------------------------------------------------------
#define NW_IN  (HIDD * IND)
#define NW_L   (3 * HIDD * HIDD)
#define NW_OUT (OUTD * CATD)
#define NW_ROW (NW_IN + NW_L + NW_OUT)
#define NW_ALL (NW_ROW + NW_L + NW_OUT)

__global__ __launch_bounds__(256)
void wsplit_k(const float* __restrict__ Wi, const float* __restrict__ Wl,
              const float* __restrict__ Wo,
              ushort* __restrict__ whi, ushort* __restrict__ wlo)
{
    int i = blockIdx.x * 256 + threadIdx.x;
    if (i >= NW_ALL) return;
    float v;
    if (i < NW_ROW) {
        if (i < NW_IN)              v = Wi[i];
        else if (i < NW_IN + NW_L)  v = Wl[i - NW_IN];
        else                        v = Wo[i - NW_IN - NW_L];
    } else if (i < NW_ROW + NW_L) {
        int fi = i - NW_ROW;
        int l  = fi / 9216;
        int r  = fi - l * 9216;
        int c  = r / 1536;
        int ks = (r % 1536) / 512;
        int ln = (r % 512) / 8;
        int t  = r & 7;
        int j  = c * 16 + (ln & 15);
        int k  = ks * 32 + 8 * (ln >> 4) + t;
        v = Wl[(l * HIDD + j) * HIDD + k];
    } else {
        int fi = i - NW_ROW - NW_L;
        int c  = fi / 6144;
        int r  = fi - c * 6144;
        int ks = r / 512;
        int ln = (r % 512) / 8;
        int t  = r & 7;
        int j  = c * 16 + (ln & 15);
        int k  = ks * 32 + 8 * (ln >> 4) + t;
        v = Wo[j * CATD + k];
    }
    ushort h = f2bf(v);
    whi[i] = h;
    wlo[i] = f2bf(v - bf2f(h));
}

// ---------------------------------------------------------------------------
// MFMA GEMM (row-major W staged in LDS), C stride parametrized.
// ---------------------------------------------------------------------------
template<int K, int NCOLS, int ROWS, bool ACCUM>
__global__ __launch_bounds__(256)
void mgemm_k(const float* __restrict__ A,
             const ushort* __restrict__ Whi, const ushort* __restrict__ Wlo,
             int wstride, const float* __restrict__ bias,
             float* __restrict__ C, int cstride, int nrows)
{
    constexpr int ST  = K + 8;
    constexpr int KS  = K / 32;
    constexpr int TRP = (ROWS / 16) / 2;
    constexpr int TCP = (NCOLS / 16) / 2;
    constexpr int CPR = K / 8;

    __shared__ __align__(16) ushort sWh[NCOLS * ST];
    __shared__ __align__(16) ushort sWl[NCOLS * ST];

    const int tid  = threadIdx.x;
    const int w    = tid >> 6;
    const int l    = tid & 63;
    const int lr   = l & 15;
    const int lg   = l >> 4;
    const int row0 = blockIdx.x * ROWS;

    for (int idx = tid; idx < NCOLS * CPR; idx += 256) {
        int j = idx / CPR, c = idx - j * CPR;
        *(uint4*)&sWh[j * ST + c * 8] = *(const uint4*)&Whi[(long)j * wstride + c * 8];
        *(uint4*)&sWl[j * ST + c * 8] = *(const uint4*)&Wlo[(long)j * wstride + c * 8];
    }

    short8v Ah[TRP][KS], Al[TRP][KS];
#pragma unroll
    for (int i = 0; i < TRP; i++) {
        const int row = row0 + ((w >> 1) + 2 * i) * 16 + lr;
#pragma unroll
        for (int ks = 0; ks < KS; ks++) {
            float4 r0 = make_float4(0.f, 0.f, 0.f, 0.f);
            float4 r1 = make_float4(0.f, 0.f, 0.f, 0.f);
            if (row < nrows) {
                const float* p = &A[(long)row * K + ks * 32 + 8 * lg];
                r0 = *(const float4*)p;
                r1 = *(const float4*)(p + 4);
            }
            const float f[8] = {r0.x, r0.y, r0.z, r0.w, r1.x, r1.y, r1.z, r1.w};
            short8v hi, lo;
#pragma unroll
            for (int t = 0; t < 8; t++) {
                ushort h = f2bf(f[t]);
                hi[t] = (short)h;
                lo[t] = (short)f2bf(f[t] - bf2f(h));
            }
            Ah[i][ks] = hi;
            Al[i][ks] = lo;
        }
    }
    __syncthreads();

#pragma unroll
    for (int j = 0; j < TCP; j++) {
        const int colb = ((w & 1) + 2 * j) * 16;
        short8v Bh[KS], Bl[KS];
#pragma unroll
        for (int ks = 0; ks < KS; ks++) {
            Bh[ks] = *(const short8v*)&sWh[(colb + lr) * ST + ks * 32 + 8 * lg];
            Bl[ks] = *(const short8v*)&sWl[(colb + lr) * ST + ks * 32 + 8 * lg];
        }
        const float bv = bias ? bias[colb + lr] : 0.f;
#pragma unroll
        for (int i = 0; i < TRP; i++) {
            f32x4 acc = {bv, bv, bv, bv};
#pragma unroll
            for (int ks = 0; ks < KS; ks++) {
                acc = __builtin_amdgcn_mfma_f32_16x16x32_bf16(Ah[i][ks], Bh[ks], acc, 0, 0, 0);
                acc = __builtin_amdgcn_mfma_f32_16x16x32_bf16(Ah[i][ks], Bl[ks], acc, 0, 0, 0);
                acc = __builtin_amdgcn_mfma_f32_16x16x32_bf16(Al[i][ks], Bh[ks], acc, 0, 0, 0);
            }
#pragma unroll
            for (int p = 0; p < 4; p++) {
                const int row = row0 + ((w >> 1) + 2 * i) * 16 + 4 * lg + p;
                if (row < nrows) {
                    float* cp = &C[(long)row * cstride + colb + lr];
                    if (ACCUM) *cp += acc[p];
                    else       *cp  = acc[p];
                }
            }
        }
    }
}

// ---------------------------------------------------------------------------
// One-pass capped-bucket CSR, 4 edges/thread.
// ---------------------------------------------------------------------------
__global__ __launch_bounds__(256)
void fillb_k(const int* __restrict__ ei, int* __restrict__ cursor,
             int* __restrict__ bucket)
{
    unsigned int e0 = (blockIdx.x * 256u + threadIdx.x) * 4u;
    if (e0 + 4 <= (unsigned int)NE) {
        const int4 s4 = *(const int4*)&ei[e0];
        const int4 d4 = *(const int4*)&ei[NE + e0];
        int p0 = atomicAdd(&cursor[d4.x], 1);
        int p1 = atomicAdd(&cursor[d4.y], 1);
        int p2 = atomicAdd(&cursor[d4.z], 1);
        int p3 = atomicAdd(&cursor[d4.w], 1);
        if (p0 < CAP) bucket[(long)d4.x * CAP + p0] = s4.x;
        if (p1 < CAP) bucket[(long)d4.y * CAP + p1] = s4.y;
        if (p2 < CAP) bucket[(long)d4.z * CAP + p2] = s4.z;
        if (p3 < CAP) bucket[(long)d4.w * CAP + p3] = s4.w;
    } else {
        for (unsigned int e = e0; e < (unsigned int)NE; e++) {
            int s = ei[e];
            int d = ei[NE + e];
            int pos = atomicAdd(&cursor[d], 1);
            if (pos < CAP) bucket[(long)d * CAP + pos] = s;
        }
    }
}

// ---------------------------------------------------------------------------
// fp32 -> bf16 copy of an h slab column block (96 cols)
// ---------------------------------------------------------------------------
__global__ __launch_bounds__(256)
void hcvt_k(const float* __restrict__ hf, int istride, ushort* __restrict__ hb)
{
    int idx = blockIdx.x * 256 + threadIdx.x;       // one per 8 elements
    if (idx >= NN * (HIDD / 8)) return;
    int row = idx / (HIDD / 8);
    int c   = (idx - row * (HIDD / 8)) * 8;
    const float* p = &hf[(long)row * istride + c];
    const float4 r0 = *(const float4*)p;
    const float4 r1 = *(const float4*)(p + 4);
    uint4 o;
    o.x = (unsigned)f2bf(r0.x) | ((unsigned)f2bf(r0.y) << 16);
    o.y = (unsigned)f2bf(r0.z) | ((unsigned)f2bf(r0.w) << 16);
    o.z = (unsigned)f2bf(r1.x) | ((unsigned)f2bf(r1.y) << 16);
    o.w = (unsigned)f2bf(r1.z) | ((unsigned)f2bf(r1.w) << 16);
    *(uint4*)&hb[(long)row * HIDD + c] = o;
}

// ---------------------------------------------------------------------------
// Fused layer v5: self term fp32 + neighbors from bf16 copy (half traffic);
// r7-proven shape: 256 thr = 32 nodes x 8 strips, 2-neighbor ILP.
// Writes fp32 h_out (+ optional bf16 copy for the next layer's gather).
// ---------------------------------------------------------------------------
#define FROWS 32
#define FAST  100

__global__ __launch_bounds__(256)
void flayer_k(const float* __restrict__ hf_in, int istride,
              const ushort* __restrict__ hb_in,
              const int* __restrict__ cursor, const int* __restrict__ bucket,
              const ushort* __restrict__ fWhi, const ushort* __restrict__ fWlo,
              const float* __restrict__ bias,
              float* __restrict__ hf_out, int ostride,
              ushort* __restrict__ hb_out)
{
    __shared__ __align__(16) float sA[FROWS * FAST];

    const int tid = threadIdx.x;
    const int n0  = blockIdx.x * FROWS;

    // gather: self (fp32) + neighbors (bf16)
    {
        const int i  = tid >> 3;
        const int st = tid & 7;
        const int n  = n0 + i;
        float4 s0 = make_float4(0.f, 0.f, 0.f, 0.f);
        float4 s1 = s0, s2 = s0;
        if (n < NN) {
            const float* hp = &hf_in[(long)n * istride + st * 12];
            s0 = ((const float4*)hp)[0];
            s1 = *(const float4*)(hp + 4);
            s2 = *(const float4*)(hp + 8);
            int cnt = cursor[n];
            if (cnt > CAP) cnt = CAP;
            const int* bp = &bucket[(long)n * CAP];
            const ushort* hbb = hb_in + st * 12;
#define ACCB(q)                                                              \
            { const uint2 a = *(const uint2*)(q);                            \
              const uint2 b = *(const uint2*)((q) + 4);                      \
              const uint2 c = *(const uint2*)((q) + 8);                      \
              s0.x += blo(a.x); s0.y += bhi(a.x); s0.z += blo(a.y); s0.w += bhi(a.y); \
              s1.x += blo(b.x); s1.y += bhi(b.x); s1.z += blo(b.y); s1.w += bhi(b.y); \
              s2.x += blo(c.x); s2.y += bhi(c.x); s2.z += blo(c.y); s2.w += bhi(c.y); }
            int e = 0;
            for (; e + 1 < cnt; e += 2) {
                const int2 id = *(const int2*)&bp[e];
                const ushort* q0 = &hbb[(long)id.x * HIDD];
                const ushort* q1 = &hbb[(long)id.y * HIDD];
                ACCB(q0); ACCB(q1);
            }
            if (e < cnt) {
                const ushort* q = &hbb[(long)bp[e] * HIDD];
                ACCB(q);
            }
#undef ACCB
        }
        float* ap = &sA[i * FAST + st * 12];
        ((float4*)ap)[0] = s0;
        ((float4*)ap)[1] = s1;
        ((float4*)ap)[2] = s2;
    }
    __syncthreads();

    const int w  = tid >> 6;
    const int l  = tid & 63;
    const int lr = l & 15;
    const int lg = l >> 4;
    const int tr = w >> 1;

    short8v Ah[3], Al[3];
#pragma unroll
    for (int ks = 0; ks < 3; ks++) {
        const float* ap = &sA[(tr * 16 + lr) * FAST + ks * 32 + 8 * lg];
        const float4 r0 = ((const float4*)ap)[0];
        const float4 r1 = ((const float4*)ap)[1];
        const float f[8] = {r0.x, r0.y, r0.z, r0.w, r1.x, r1.y, r1.z, r1.w};
        short8v hi, lo;
#pragma unroll
        for (int t = 0; t < 8; t++) {
            ushort h = f2bf(f[t]);
            hi[t] = (short)h;
            lo[t] = (short)f2bf(f[t] - bf2f(h));
        }
        Ah[ks] = hi;
        Al[ks] = lo;
    }

#pragma unroll
    for (int j = 0; j < 3; j++) {
        const int c    = (w & 1) + 2 * j;
        const int colb = c * 16;
        short8v Bh[3], Bl[3];
#pragma unroll
        for (int ks = 0; ks < 3; ks++) {
            Bh[ks] = *(const short8v*)&fWhi[((c * 3 + ks) * 64 + l) * 8];
            Bl[ks] = *(const short8v*)&fWlo[((c * 3 + ks) * 64 + l) * 8];
        }
        const float bv = bias[colb + lr];
        f32x4 acc = {bv, bv, bv, bv};
#pragma unroll
        for (int ks = 0; ks < 3; ks++) {
            acc = __builtin_amdgcn_mfma_f32_16x16x32_bf16(Ah[ks], Bh[ks], acc, 0, 0, 0);
            acc = __builtin_amdgcn_mfma_f32_16x16x32_bf16(Ah[ks], Bl[ks], acc, 0, 0, 0);
            acc = __builtin_amdgcn_mfma_f32_16x16x32_bf16(Al[ks], Bh[ks], acc, 0, 0, 0);
        }
#pragma unroll
        for (int p = 0; p < 4; p++) {
            const int row = n0 + tr * 16 + 4 * lg + p;
            if (row < NN) {
                hf_out[(long)row * ostride + colb + lr] = acc[p];
                if (hb_out)
                    hb_out[(long)row * HIDD + colb + lr] = f2bf(acc[p]);
            }
        }
    }
}

// ---------------------------------------------------------------------------
// Final GEMM: out[NN][128] = cat[NN][384] @ W_out^T + b_out
// ---------------------------------------------------------------------------
__global__ __launch_bounds__(256)
void fgemm_k(const float* __restrict__ cat, const ushort* __restrict__ fOhi,
             const ushort* __restrict__ fOlo, const float* __restrict__ bias,
             float* __restrict__ out)
{
    const int tid  = threadIdx.x;
    const int w    = tid >> 6;
    const int l    = tid & 63;
    const int lr   = l & 15;
    const int lg   = l >> 4;
    const int row0 = blockIdx.x * 64;

    f32x4 acc[2][4];
#pragma unroll
    for (int j = 0; j < 4; j++) {
        const float bv = bias[((w & 1) + 2 * j) * 16 + lr];
#pragma unroll
        for (int i = 0; i < 2; i++) acc[i][j] = (f32x4){bv, bv, bv, bv};
    }

#pragma unroll 4
    for (int ks = 0; ks < 12; ks++) {
        short8v Ah[2], Al[2];
#pragma unroll
        for (int i = 0; i < 2; i++) {
            const int row = row0 + ((w >> 1) + 2 * i) * 16 + lr;
            float4 r0 = make_float4(0.f, 0.f, 0.f, 0.f);
            float4 r1 = make_float4(0.f, 0.f, 0.f, 0.f);
            if (row < NN) {
                const float* p = &cat[(long)row * CATD + ks * 32 + 8 * lg];
                r0 = *(const float4*)p;
                r1 = *(const float4*)(p + 4);
            }
            const float f[8] = {r0.x, r0.y, r0.z, r0.w, r1.x, r1.y, r1.z, r1.w};
            short8v hi, lo;
#pragma unroll
            for (int t = 0; t < 8; t++) {
                ushort h = f2bf(f[t]);
                hi[t] = (short)h;
                lo[t] = (short)f2bf(f[t] - bf2f(h));
            }
            Ah[i] = hi;
            Al[i] = lo;
        }
#pragma unroll
        for (int j = 0; j < 4; j++) {
            const int c = (w & 1) + 2 * j;
            const short8v Bh = *(const short8v*)&fOhi[((c * 12 + ks) * 64 + l) * 8];
            const short8v Bl = *(const short8v*)&fOlo[((c * 12 + ks) * 64 + l) * 8];
#pragma unroll
            for (int i = 0; i < 2; i++) {
                acc[i][j] = __builtin_amdgcn_mfma_f32_16x16x32_bf16(Ah[i], Bh, acc[i][j], 0, 0, 0);
                acc[i][j] = __builtin_amdgcn_mfma_f32_16x16x32_bf16(Ah[i], Bl, acc[i][j], 0, 0, 0);
                acc[i][j] = __builtin_amdgcn_mfma_f32_16x16x32_bf16(Al[i], Bh, acc[i][j], 0, 0, 0);
            }
        }
    }

#pragma unroll
    for (int i = 0; i < 2; i++) {
#pragma unroll
        for (int p = 0; p < 4; p++) {
            const int row = row0 + ((w >> 1) + 2 * i) * 16 + 4 * lg + p;
            if (row < NN) {
#pragma unroll
                for (int j = 0; j < 4; j++)
                    out[(long)row * OUTD + ((w & 1) + 2 * j) * 16 + lr] = acc[i][j][p];
            }
        }
    }
}

// ---------------------------------------------------------------------------
extern "C" void kernel_launch(void* const* d_in, const int* in_sizes, int n_in,
                              void* d_out, int out_size, void* d_ws, size_t ws_size,
                              hipStream_t stream)
{
    const float* x  = (const float*)d_in[0];
    const int*   ei = (const int*)  d_in[1];
    const float* Wi = (const float*)d_in[2];
    const float* bi = (const float*)d_in[3];
    const float* Wl = (const float*)d_in[4];
    const float* bl = (const float*)d_in[5];
    const float* Wo = (const float*)d_in[6];
    const float* bo = (const float*)d_in[7];
    float* out = (float*)d_out;

    char* p = (char*)d_ws;
    int* cursor = (int*)p;                 p += ((size_t)NN * 4 + 255) & ~255ull;
    int* bucket = (int*)p;                 p += ((size_t)NN * CAP * 4 + 255) & ~255ull;
    ushort* whi = (ushort*)p;              p += ((size_t)NW_ALL * 2 + 255) & ~255ull;
    ushort* wlo = (ushort*)p;              p += ((size_t)NW_ALL * 2 + 255) & ~255ull;
    ushort* hbfA = (ushort*)p;             p += ((size_t)NN * HIDD * 2 + 255) & ~255ull;
    ushort* hbfB = (ushort*)p;             p += ((size_t)NN * HIDD * 2 + 255) & ~255ull;
    float* big  = (float*)p;
    const size_t used = (size_t)(p - (char*)d_ws);
    const bool catpath = (ws_size >= used + (size_t)NN * CATD * 4);

    const ushort* whi_in = whi;
    const ushort* wlo_in = wlo;
    const ushort* whi_o  = whi + NW_IN + NW_L;
    const ushort* wlo_o  = wlo + NW_IN + NW_L;
    const ushort* fLhi   = whi + NW_ROW;
    const ushort* fLlo   = wlo + NW_ROW;
    const ushort* fOhi   = whi + NW_ROW + NW_L;
    const ushort* fOlo   = wlo + NW_ROW + NW_L;

    hipLaunchKernelGGL(wsplit_k, dim3((NW_ALL + 255) / 256), dim3(256), 0, stream,
                       Wi, Wl, Wo, whi, wlo);
    hipMemsetAsync(cursor, 0, (size_t)NN * sizeof(int), stream);
    hipLaunchKernelGGL(fillb_k, dim3((NE / 4 + 255) / 256), dim3(256), 0, stream,
                       ei, cursor, bucket);

    if (catpath) {
        float* cat = big;                          // [NN][384]
        hipLaunchKernelGGL((mgemm_k<IND, HIDD, 32, false>),
                           dim3((NN + 31) / 32), dim3(256), 0, stream,
                           x, whi_in, wlo_in, IND, bi, cat, CATD, NN);
        hipLaunchKernelGGL(hcvt_k, dim3((NN * (HIDD / 8) + 255) / 256), dim3(256), 0, stream,
                           cat, CATD, hbfA);
        // l=0
        hipLaunchKernelGGL(flayer_k, dim3((NN + FROWS - 1) / FROWS), dim3(256), 0, stream,
                           cat, CATD, hbfA, cursor, bucket,
                           fLhi, fLlo, bl, cat + HIDD, CATD, hbfB);
        // l=1
        hipLaunchKernelGGL(flayer_k, dim3((NN + FROWS - 1) / FROWS), dim3(256), 0, stream,
                           cat + HIDD, CATD, hbfB, cursor, bucket,
                           fLhi + 9216, fLlo + 9216, bl + HIDD,
                           cat + 2 * HIDD, CATD, hbfA);
        // l=2 (no bf16 copy needed)
        hipLaunchKernelGGL(flayer_k, dim3((NN + FROWS - 1) / FROWS), dim3(256), 0, stream,
                           cat + 2 * HIDD, CATD, hbfA, cursor, bucket,
                           fLhi + 2 * 9216, fLlo + 2 * 9216, bl + 2 * HIDD,
                           cat + 3 * HIDD, CATD, (ushort*)nullptr);
        hipLaunchKernelGGL(fgemm_k, dim3((NN + 63) / 64), dim3(256), 0, stream,
                           cat, fOhi, fOlo, bo, out);
    } else {
        float* hA = big;                           // [NN][96]
        float* hB = hA + (size_t)NN * HIDD;        // [NN][96]
        hipLaunchKernelGGL((mgemm_k<IND, HIDD, 32, false>),
                           dim3((NN + 31) / 32), dim3(256), 0, stream,
                           x, whi_in, wlo_in, IND, bi, hA, HIDD, NN);
        hipLaunchKernelGGL((mgemm_k<HIDD, OUTD, 64, false>),
                           dim3((NN + 63) / 64), dim3(256), 0, stream,
                           hA, whi_o, wlo_o, CATD, bo, out, OUTD, NN);
        hipLaunchKernelGGL(hcvt_k, dim3((NN * (HIDD / 8) + 255) / 256), dim3(256), 0, stream,
                           hA, HIDD, hbfA);
        const float* hsrc = hA;  float* hdst = hB;
        ushort* bsrc = hbfA;     ushort* bdst = hbfB;
        for (int l = 0; l < 3; l++) {
            hipLaunchKernelGGL(flayer_k, dim3((NN + FROWS - 1) / FROWS), dim3(256), 0, stream,
                               hsrc, HIDD, bsrc, cursor, bucket,
                               fLhi + (size_t)l * 9216, fLlo + (size_t)l * 9216,
                               bl + (size_t)l * HIDD, hdst, HIDD,
                               (l < 2) ? bdst : (ushort*)nullptr);
            hipLaunchKernelGGL((mgemm_k<HIDD, OUTD, 64, true>),
                               dim3((NN + 63) / 64), dim3(256), 0, stream,
                               hdst, whi_o + (size_t)(l + 1) * HIDD,
                               wlo_o + (size_t)(l + 1) * HIDD, CATD,
                               (const float*)nullptr, out, OUTD, NN);
            const float* t = hsrc; hsrc = hdst; hdst = (float*)t;
            ushort* tb = bsrc; bsrc = bdst; bdst = tb;
        }
    }
}

// Round 10
// 316.926 us; speedup vs baseline: 1.2427x; 1.0405x over previous
//
#include <hip/hip_runtime.h>

#define NN   50000
#define NE   800000
#define IND  128
#define HIDD 96
#define OUTD 128
#define CATD (4 * HIDD)   // 384
#define CAP  64

typedef __attribute__((ext_vector_type(8))) short short8v;
typedef __attribute__((ext_vector_type(4))) float f32x4;

__device__ __forceinline__ ushort f2bf(float f) {
    unsigned u = __float_as_uint(f);
    u = (u + 0x7FFFu + ((u >> 16) & 1u)) >> 16;
    return (ushort)u;
}
__device__ __forceinline__ float bf2f(ushort h) {
    return __uint_as_float(((unsigned)h) << 16);
}
__device__ __forceinline__ float blo(unsigned u) { return __uint_as_float(u << 16); }
__device__ __forceinline__ float bhi(unsigned u) { return __uint_as_float(u & 0xffff0000u); }

// ---------------------------------------------------------------------------
// Weight regions (in whi/wlo):
//  [0, NW_IN)                row-major W_in   [96][128]
//  [NW_IN, NW_IN+NW_L)       row-major W_layers
//  [.., NW_ROW)              row-major W_out  [128][384]
//  [NW_ROW, NW_ROW+NW_L)     frag-ordered W_layers: [l][c<6][ks<3][lane<64][8]
//  [NW_ROW+NW_L, NW_ALL)     frag-ordered W_out:    [c<8][ks<12][lane<64][8]
// ---------------------------------------------------------------------------
#define NW_IN  (HIDD * IND)
#define NW_L   (3 * HIDD * HIDD)
#define NW_OUT (OUTD * CATD)
#define NW_ROW (NW_IN + NW_L + NW_OUT)
#define NW_ALL (NW_ROW + NW_L + NW_OUT)

__global__ __launch_bounds__(256)
void wsplit_k(const float* __restrict__ Wi, const float* __restrict__ Wl,
              const float* __restrict__ Wo,
              ushort* __restrict__ whi, ushort* __restrict__ wlo)
{
    int i = blockIdx.x * 256 + threadIdx.x;
    if (i >= NW_ALL) return;
    float v;
    if (i < NW_ROW) {
        if (i < NW_IN)              v = Wi[i];
        else if (i < NW_IN + NW_L)  v = Wl[i - NW_IN];
        else                        v = Wo[i - NW_IN - NW_L];
    } else if (i < NW_ROW + NW_L) {
        int fi = i - NW_ROW;
        int l  = fi / 9216;
        int r  = fi - l * 9216;
        int c  = r / 1536;
        int ks = (r % 1536) / 512;
        int ln = (r % 512) / 8;
        int t  = r & 7;
        int j  = c * 16 + (ln & 15);
        int k  = ks * 32 + 8 * (ln >> 4) + t;
        v = Wl[(l * HIDD + j) * HIDD + k];
    } else {
        int fi = i - NW_ROW - NW_L;
        int c  = fi / 6144;
        int r  = fi - c * 6144;
        int ks = r / 512;
        int ln = (r % 512) / 8;
        int t  = r & 7;
        int j  = c * 16 + (ln & 15);
        int k  = ks * 32 + 8 * (ln >> 4) + t;
        v = Wo[j * CATD + k];
    }
    ushort h = f2bf(v);
    whi[i] = h;
    wlo[i] = f2bf(v - bf2f(h));
}

// ---------------------------------------------------------------------------
// MFMA GEMM (row-major W staged in LDS), C stride parametrized.
// ---------------------------------------------------------------------------
template<int K, int NCOLS, int ROWS, bool ACCUM>
__global__ __launch_bounds__(256)
void mgemm_k(const float* __restrict__ A,
             const ushort* __restrict__ Whi, const ushort* __restrict__ Wlo,
             int wstride, const float* __restrict__ bias,
             float* __restrict__ C, int cstride, int nrows)
{
    constexpr int ST  = K + 8;
    constexpr int KS  = K / 32;
    constexpr int TRP = (ROWS / 16) / 2;
    constexpr int TCP = (NCOLS / 16) / 2;
    constexpr int CPR = K / 8;

    __shared__ __align__(16) ushort sWh[NCOLS * ST];
    __shared__ __align__(16) ushort sWl[NCOLS * ST];

    const int tid  = threadIdx.x;
    const int w    = tid >> 6;
    const int l    = tid & 63;
    const int lr   = l & 15;
    const int lg   = l >> 4;
    const int row0 = blockIdx.x * ROWS;

    for (int idx = tid; idx < NCOLS * CPR; idx += 256) {
        int j = idx / CPR, c = idx - j * CPR;
        *(uint4*)&sWh[j * ST + c * 8] = *(const uint4*)&Whi[(long)j * wstride + c * 8];
        *(uint4*)&sWl[j * ST + c * 8] = *(const uint4*)&Wlo[(long)j * wstride + c * 8];
    }

    short8v Ah[TRP][KS], Al[TRP][KS];
#pragma unroll
    for (int i = 0; i < TRP; i++) {
        const int row = row0 + ((w >> 1) + 2 * i) * 16 + lr;
#pragma unroll
        for (int ks = 0; ks < KS; ks++) {
            float4 r0 = make_float4(0.f, 0.f, 0.f, 0.f);
            float4 r1 = make_float4(0.f, 0.f, 0.f, 0.f);
            if (row < nrows) {
                const float* p = &A[(long)row * K + ks * 32 + 8 * lg];
                r0 = *(const float4*)p;
                r1 = *(const float4*)(p + 4);
            }
            const float f[8] = {r0.x, r0.y, r0.z, r0.w, r1.x, r1.y, r1.z, r1.w};
            short8v hi, lo;
#pragma unroll
            for (int t = 0; t < 8; t++) {
                ushort h = f2bf(f[t]);
                hi[t] = (short)h;
                lo[t] = (short)f2bf(f[t] - bf2f(h));
            }
            Ah[i][ks] = hi;
            Al[i][ks] = lo;
        }
    }
    __syncthreads();

#pragma unroll
    for (int j = 0; j < TCP; j++) {
        const int colb = ((w & 1) + 2 * j) * 16;
        short8v Bh[KS], Bl[KS];
#pragma unroll
        for (int ks = 0; ks < KS; ks++) {
            Bh[ks] = *(const short8v*)&sWh[(colb + lr) * ST + ks * 32 + 8 * lg];
            Bl[ks] = *(const short8v*)&sWl[(colb + lr) * ST + ks * 32 + 8 * lg];
        }
        const float bv = bias ? bias[colb + lr] : 0.f;
#pragma unroll
        for (int i = 0; i < TRP; i++) {
            f32x4 acc = {bv, bv, bv, bv};
#pragma unroll
            for (int ks = 0; ks < KS; ks++) {
                acc = __builtin_amdgcn_mfma_f32_16x16x32_bf16(Ah[i][ks], Bh[ks], acc, 0, 0, 0);
                acc = __builtin_amdgcn_mfma_f32_16x16x32_bf16(Ah[i][ks], Bl[ks], acc, 0, 0, 0);
                acc = __builtin_amdgcn_mfma_f32_16x16x32_bf16(Al[i][ks], Bh[ks], acc, 0, 0, 0);
            }
#pragma unroll
            for (int p = 0; p < 4; p++) {
                const int row = row0 + ((w >> 1) + 2 * i) * 16 + 4 * lg + p;
                if (row < nrows) {
                    float* cp = &C[(long)row * cstride + colb + lr];
                    if (ACCUM) *cp += acc[p];
                    else       *cp  = acc[p];
                }
            }
        }
    }
}

// ---------------------------------------------------------------------------
// One-pass capped-bucket CSR; ushort indices (src < 50000 < 65536).
// 1 edge/thread (r9's x4 coarsening measured slower: grid too small).
// ---------------------------------------------------------------------------
__global__ __launch_bounds__(256)
void fillb_k(const int* __restrict__ ei, int* __restrict__ cursor,
             ushort* __restrict__ bucket)
{
    unsigned int e = blockIdx.x * 256u + threadIdx.x;
    if (e < (unsigned int)NE) {
        int s = ei[e];
        int d = ei[NE + e];
        int pos = atomicAdd(&cursor[d], 1);
        if (pos < CAP) bucket[(long)d * CAP + pos] = (ushort)s;
    }
}

// ---------------------------------------------------------------------------
// fp32 -> bf16 copy of an h slab column block (96 cols)
// ---------------------------------------------------------------------------
__global__ __launch_bounds__(256)
void hcvt_k(const float* __restrict__ hf, int istride, ushort* __restrict__ hb)
{
    int idx = blockIdx.x * 256 + threadIdx.x;
    if (idx >= NN * (HIDD / 8)) return;
    int row = idx / (HIDD / 8);
    int c   = (idx - row * (HIDD / 8)) * 8;
    const float* p = &hf[(long)row * istride + c];
    const float4 r0 = *(const float4*)p;
    const float4 r1 = *(const float4*)(p + 4);
    uint4 o;
    o.x = (unsigned)f2bf(r0.x) | ((unsigned)f2bf(r0.y) << 16);
    o.y = (unsigned)f2bf(r0.z) | ((unsigned)f2bf(r0.w) << 16);
    o.z = (unsigned)f2bf(r1.x) | ((unsigned)f2bf(r1.y) << 16);
    o.w = (unsigned)f2bf(r1.z) | ((unsigned)f2bf(r1.w) << 16);
    *(uint4*)&hb[(long)row * HIDD + c] = o;
}

// ---------------------------------------------------------------------------
// Fused layer: self fp32 + neighbors bf16; ushort bucket (pair-packed loads).
// 256 thr = 32 nodes x 8 strips.
// ---------------------------------------------------------------------------
#define FROWS 32
#define FAST  100

__global__ __launch_bounds__(256)
void flayer_k(const float* __restrict__ hf_in, int istride,
              const ushort* __restrict__ hb_in,
              const int* __restrict__ cursor, const ushort* __restrict__ bucket,
              const ushort* __restrict__ fWhi, const ushort* __restrict__ fWlo,
              const float* __restrict__ bias,
              float* __restrict__ hf_out, int ostride,
              ushort* __restrict__ hb_out)
{
    __shared__ __align__(16) float sA[FROWS * FAST];

    const int tid = threadIdx.x;
    const int n0  = blockIdx.x * FROWS;

    {
        const int i  = tid >> 3;
        const int st = tid & 7;
        const int n  = n0 + i;
        float4 s0 = make_float4(0.f, 0.f, 0.f, 0.f);
        float4 s1 = s0, s2 = s0;
        if (n < NN) {
            const float* hp = &hf_in[(long)n * istride + st * 12];
            s0 = ((const float4*)hp)[0];
            s1 = *(const float4*)(hp + 4);
            s2 = *(const float4*)(hp + 8);
            int cnt = cursor[n];
            if (cnt > CAP) cnt = CAP;
            const ushort* bp = &bucket[(long)n * CAP];
            const ushort* hbb = hb_in + st * 12;
#define ACCB(q)                                                              \
            { const uint2 a = *(const uint2*)(q);                            \
              const uint2 b = *(const uint2*)((q) + 4);                      \
              const uint2 c = *(const uint2*)((q) + 8);                      \
              s0.x += blo(a.x); s0.y += bhi(a.x); s0.z += blo(a.y); s0.w += bhi(a.y); \
              s1.x += blo(b.x); s1.y += bhi(b.x); s1.z += blo(b.y); s1.w += bhi(b.y); \
              s2.x += blo(c.x); s2.y += bhi(c.x); s2.z += blo(c.y); s2.w += bhi(c.y); }
            int e = 0;
            for (; e + 1 < cnt; e += 2) {
                const unsigned id2 = *(const unsigned*)&bp[e];   // e even: aligned
                const ushort* q0 = &hbb[(long)(id2 & 0xffffu) * HIDD];
                const ushort* q1 = &hbb[(long)(id2 >> 16) * HIDD];
                ACCB(q0); ACCB(q1);
            }
            if (e < cnt) {
                const ushort* q = &hbb[(long)bp[e] * HIDD];
                ACCB(q);
            }
#undef ACCB
        }
        float* ap = &sA[i * FAST + st * 12];
        ((float4*)ap)[0] = s0;
        ((float4*)ap)[1] = s1;
        ((float4*)ap)[2] = s2;
    }
    __syncthreads();

    const int w  = tid >> 6;
    const int l  = tid & 63;
    const int lr = l & 15;
    const int lg = l >> 4;
    const int tr = w >> 1;

    short8v Ah[3], Al[3];
#pragma unroll
    for (int ks = 0; ks < 3; ks++) {
        const float* ap = &sA[(tr * 16 + lr) * FAST + ks * 32 + 8 * lg];
        const float4 r0 = ((const float4*)ap)[0];
        const float4 r1 = ((const float4*)ap)[1];
        const float f[8] = {r0.x, r0.y, r0.z, r0.w, r1.x, r1.y, r1.z, r1.w};
        short8v hi, lo;
#pragma unroll
        for (int t = 0; t < 8; t++) {
            ushort h = f2bf(f[t]);
            hi[t] = (short)h;
            lo[t] = (short)f2bf(f[t] - bf2f(h));
        }
        Ah[ks] = hi;
        Al[ks] = lo;
    }

#pragma unroll
    for (int j = 0; j < 3; j++) {
        const int c    = (w & 1) + 2 * j;
        const int colb = c * 16;
        short8v Bh[3], Bl[3];
#pragma unroll
        for (int ks = 0; ks < 3; ks++) {
            Bh[ks] = *(const short8v*)&fWhi[((c * 3 + ks) * 64 + l) * 8];
            Bl[ks] = *(const short8v*)&fWlo[((c * 3 + ks) * 64 + l) * 8];
        }
        const float bv = bias[colb + lr];
        f32x4 acc = {bv, bv, bv, bv};
#pragma unroll
        for (int ks = 0; ks < 3; ks++) {
            acc = __builtin_amdgcn_mfma_f32_16x16x32_bf16(Ah[ks], Bh[ks], acc, 0, 0, 0);
            acc = __builtin_amdgcn_mfma_f32_16x16x32_bf16(Ah[ks], Bl[ks], acc, 0, 0, 0);
            acc = __builtin_amdgcn_mfma_f32_16x16x32_bf16(Al[ks], Bh[ks], acc, 0, 0, 0);
        }
#pragma unroll
        for (int p = 0; p < 4; p++) {
            const int row = n0 + tr * 16 + 4 * lg + p;
            if (row < NN) {
                hf_out[(long)row * ostride + colb + lr] = acc[p];
                if (hb_out)
                    hb_out[(long)row * HIDD + colb + lr] = f2bf(acc[p]);
            }
        }
    }
}

// ---------------------------------------------------------------------------
// Final GEMM: out[NN][128] = cat[NN][384] @ W_out^T + b_out
// 32 rows/block (grid 1563: fixes r9's grid-limited 17% occupancy).
// Wave w: row tile = w>>1, col half = w&1; one A-conversion per ks per wave.
// ---------------------------------------------------------------------------
__global__ __launch_bounds__(256)
void fgemm_k(const float* __restrict__ cat, const ushort* __restrict__ fOhi,
             const ushort* __restrict__ fOlo, const float* __restrict__ bias,
             float* __restrict__ out)
{
    const int tid  = threadIdx.x;
    const int w    = tid >> 6;
    const int l    = tid & 63;
    const int lr   = l & 15;
    const int lg   = l >> 4;
    const int row0 = blockIdx.x * 32;
    const int rt   = w >> 1;
    const int ch   = w & 1;
    const int arow = row0 + rt * 16 + lr;

    f32x4 acc[4];
#pragma unroll
    for (int j = 0; j < 4; j++) {
        const float bv = bias[(ch + 2 * j) * 16 + lr];
        acc[j] = (f32x4){bv, bv, bv, bv};
    }

#pragma unroll 4
    for (int ks = 0; ks < 12; ks++) {
        float4 r0 = make_float4(0.f, 0.f, 0.f, 0.f);
        float4 r1 = make_float4(0.f, 0.f, 0.f, 0.f);
        if (arow < NN) {
            const float* p = &cat[(long)arow * CATD + ks * 32 + 8 * lg];
            r0 = *(const float4*)p;
            r1 = *(const float4*)(p + 4);
        }
        const float f[8] = {r0.x, r0.y, r0.z, r0.w, r1.x, r1.y, r1.z, r1.w};
        short8v Ah, Al;
#pragma unroll
        for (int t = 0; t < 8; t++) {
            ushort h = f2bf(f[t]);
            Ah[t] = (short)h;
            Al[t] = (short)f2bf(f[t] - bf2f(h));
        }
#pragma unroll
        for (int j = 0; j < 4; j++) {
            const int c = ch + 2 * j;
            const short8v Bh = *(const short8v*)&fOhi[((c * 12 + ks) * 64 + l) * 8];
            const short8v Bl = *(const short8v*)&fOlo[((c * 12 + ks) * 64 + l) * 8];
            acc[j] = __builtin_amdgcn_mfma_f32_16x16x32_bf16(Ah, Bh, acc[j], 0, 0, 0);
            acc[j] = __builtin_amdgcn_mfma_f32_16x16x32_bf16(Ah, Bl, acc[j], 0, 0, 0);
            acc[j] = __builtin_amdgcn_mfma_f32_16x16x32_bf16(Al, Bh, acc[j], 0, 0, 0);
        }
    }

#pragma unroll
    for (int p = 0; p < 4; p++) {
        const int row = row0 + rt * 16 + 4 * lg + p;
        if (row < NN) {
#pragma unroll
            for (int j = 0; j < 4; j++)
                out[(long)row * OUTD + (ch + 2 * j) * 16 + lr] = acc[j][p];
        }
    }
}

// ---------------------------------------------------------------------------
extern "C" void kernel_launch(void* const* d_in, const int* in_sizes, int n_in,
                              void* d_out, int out_size, void* d_ws, size_t ws_size,
                              hipStream_t stream)
{
    const float* x  = (const float*)d_in[0];
    const int*   ei = (const int*)  d_in[1];
    const float* Wi = (const float*)d_in[2];
    const float* bi = (const float*)d_in[3];
    const float* Wl = (const float*)d_in[4];
    const float* bl = (const float*)d_in[5];
    const float* Wo = (const float*)d_in[6];
    const float* bo = (const float*)d_in[7];
    float* out = (float*)d_out;

    char* p = (char*)d_ws;
    int* cursor    = (int*)p;              p += ((size_t)NN * 4 + 255) & ~255ull;
    ushort* bucket = (ushort*)p;           p += ((size_t)NN * CAP * 2 + 255) & ~255ull;
    ushort* whi = (ushort*)p;              p += ((size_t)NW_ALL * 2 + 255) & ~255ull;
    ushort* wlo = (ushort*)p;              p += ((size_t)NW_ALL * 2 + 255) & ~255ull;
    ushort* hbfA = (ushort*)p;             p += ((size_t)NN * HIDD * 2 + 255) & ~255ull;
    ushort* hbfB = (ushort*)p;             p += ((size_t)NN * HIDD * 2 + 255) & ~255ull;
    float* big  = (float*)p;
    const size_t used = (size_t)(p - (char*)d_ws);
    const bool catpath = (ws_size >= used + (size_t)NN * CATD * 4);

    const ushort* whi_in = whi;
    const ushort* wlo_in = wlo;
    const ushort* whi_o  = whi + NW_IN + NW_L;
    const ushort* wlo_o  = wlo + NW_IN + NW_L;
    const ushort* fLhi   = whi + NW_ROW;
    const ushort* fLlo   = wlo + NW_ROW;
    const ushort* fOhi   = whi + NW_ROW + NW_L;
    const ushort* fOlo   = wlo + NW_ROW + NW_L;

    hipLaunchKernelGGL(wsplit_k, dim3((NW_ALL + 255) / 256), dim3(256), 0, stream,
                       Wi, Wl, Wo, whi, wlo);
    hipMemsetAsync(cursor, 0, (size_t)NN * sizeof(int), stream);
    hipLaunchKernelGGL(fillb_k, dim3((NE + 255) / 256), dim3(256), 0, stream,
                       ei, cursor, bucket);

    if (catpath) {
        float* cat = big;                          // [NN][384]
        hipLaunchKernelGGL((mgemm_k<IND, HIDD, 32, false>),
                           dim3((NN + 31) / 32), dim3(256), 0, stream,
                           x, whi_in, wlo_in, IND, bi, cat, CATD, NN);
        hipLaunchKernelGGL(hcvt_k, dim3((NN * (HIDD / 8) + 255) / 256), dim3(256), 0, stream,
                           cat, CATD, hbfA);
        hipLaunchKernelGGL(flayer_k, dim3((NN + FROWS - 1) / FROWS), dim3(256), 0, stream,
                           cat, CATD, hbfA, cursor, bucket,
                           fLhi, fLlo, bl, cat + HIDD, CATD, hbfB);
        hipLaunchKernelGGL(flayer_k, dim3((NN + FROWS - 1) / FROWS), dim3(256), 0, stream,
                           cat + HIDD, CATD, hbfB, cursor, bucket,
                           fLhi + 9216, fLlo + 9216, bl + HIDD,
                           cat + 2 * HIDD, CATD, hbfA);
        hipLaunchKernelGGL(flayer_k, dim3((NN + FROWS - 1) / FROWS), dim3(256), 0, stream,
                           cat + 2 * HIDD, CATD, hbfA, cursor, bucket,
                           fLhi + 2 * 9216, fLlo + 2 * 9216, bl + 2 * HIDD,
                           cat + 3 * HIDD, CATD, (ushort*)nullptr);
        hipLaunchKernelGGL(fgemm_k, dim3((NN + 31) / 32), dim3(256), 0, stream,
                           cat, fOhi, fOlo, bo, out);
    } else {
        float* hA = big;                           // [NN][96]
        float* hB = hA + (size_t)NN * HIDD;        // [NN][96]
        hipLaunchKernelGGL((mgemm_k<IND, HIDD, 32, false>),
                           dim3((NN + 31) / 32), dim3(256), 0, stream,
                           x, whi_in, wlo_in, IND, bi, hA, HIDD, NN);
        hipLaunchKernelGGL((mgemm_k<HIDD, OUTD, 64, false>),
                           dim3((NN + 63) / 64), dim3(256), 0, stream,
                           hA, whi_o, wlo_o, CATD, bo, out, OUTD, NN);
        hipLaunchKernelGGL(hcvt_k, dim3((NN * (HIDD / 8) + 255) / 256), dim3(256), 0, stream,
                           hA, HIDD, hbfA);
        const float* hsrc = hA;  float* hdst = hB;
        ushort* bsrc = hbfA;     ushort* bdst = hbfB;
        for (int l = 0; l < 3; l++) {
            hipLaunchKernelGGL(flayer_k, dim3((NN + FROWS - 1) / FROWS), dim3(256), 0, stream,
                               hsrc, HIDD, bsrc, cursor, bucket,
                               fLhi + (size_t)l * 9216, fLlo + (size_t)l * 9216,
                               bl + (size_t)l * HIDD, hdst, HIDD,
                               (l < 2) ? bdst : (ushort*)nullptr);
            hipLaunchKernelGGL((mgemm_k<HIDD, OUTD, 64, true>),
                               dim3((NN + 63) / 64), dim3(256), 0, stream,
                               hdst, whi_o + (size_t)(l + 1) * HIDD,
                               wlo_o + (size_t)(l + 1) * HIDD, CATD,
                               (const float*)nullptr, out, OUTD, NN);
            const float* t = hsrc; hsrc = hdst; hdst = (float*)t;
            ushort* tb = bsrc; bsrc = bdst; bdst = tb;
        }
    }
}